// Round 1
// baseline (5130.490 us; speedup 1.0000x reference)
//
#include <hip/hip_runtime.h>
#include <math.h>

#define BN 32
#define TN 128
#define ENCD 1024
#define HID 320
#define NG 1280       // 4*HID
#define VN 29
#define BLANKI 28
#define SLICES 8
#define UPS 40        // hidden units per slice
#define ROWS 160      // gate rows per slice (4*UPS)
#define JW 1344       // ENC+HID

// workspace layout (in floats)
#define E_OFF   0
#define E_SZ    (TN*BN*VN)          // 118784
#define P_OFF   (E_OFF + E_SZ)
#define P_SZ    (VN*NG)             // 37120
#define H2_OFF  (P_OFF + P_SZ)
#define H2_SZ   (2*BN*HID)          // 20480
#define PL_OFF  (H2_OFF + H2_SZ)
#define PL_SZ   (2*BN*SLICES*VN)    // 14848
#define TAG_OFF (PL_OFF + PL_SZ)    // 256 ints live here

__device__ __forceinline__ float dot4(float4 a, float4 b) {
    return a.x*b.x + a.y*b.y + a.z*b.z + a.w*b.w;
}

// K1: E[t][b][v] = b_joint[v] + x[t][b][:1024] . W_joint[v][:1024]; also resets tags.
__global__ __launch_bounds__(256) void k_enc(const float* __restrict__ x,
        const float* __restrict__ Wj, const float* __restrict__ bj,
        float* __restrict__ E, int* __restrict__ tags)
{
    __shared__ float xl[4][1056];   // 4 batch rows, padded every 128 floats by 4
    const int tid = threadIdx.x;
    const int blk = blockIdx.x;
    const int t = blk >> 3, b0 = (blk & 7) * 4;

    if (blk == 0 && tid < BN*SLICES) tags[tid] = 0;

    #pragma unroll
    for (int bb = 0; bb < 4; ++bb) {
        const float4* src = (const float4*)(x + ((size_t)(t*BN + b0 + bb))*ENCD);
        float4 v4 = src[tid];
        ((float4*)&xl[bb][0])[tid + (tid >> 5)] = v4;   // padded store
    }
    __syncthreads();
    if (tid < 232) {
        const int v = tid >> 3, k8 = tid & 7;
        float a0=0.f, a1=0.f, a2=0.f, a3=0.f;
        const float4* wrow = (const float4*)(Wj + (size_t)v*JW) + k8*32;
        const float4* x0 = ((const float4*)&xl[0][0]) + k8*33;
        const float4* x1 = ((const float4*)&xl[1][0]) + k8*33;
        const float4* x2 = ((const float4*)&xl[2][0]) + k8*33;
        const float4* x3 = ((const float4*)&xl[3][0]) + k8*33;
        #pragma unroll 4
        for (int m = 0; m < 32; ++m) {
            float4 w4 = wrow[m];
            a0 += dot4(w4, x0[m]);
            a1 += dot4(w4, x1[m]);
            a2 += dot4(w4, x2[m]);
            a3 += dot4(w4, x3[m]);
        }
        #pragma unroll
        for (int d = 1; d < 8; d <<= 1) {
            a0 += __shfl_xor(a0, d); a1 += __shfl_xor(a1, d);
            a2 += __shfl_xor(a2, d); a3 += __shfl_xor(a3, d);
        }
        if (k8 == 0) {
            float bjv = bj[v];
            E[((size_t)(t*BN + b0+0))*VN + v] = a0 + bjv;
            E[((size_t)(t*BN + b0+1))*VN + v] = a1 + bjv;
            E[((size_t)(t*BN + b0+2))*VN + v] = a2 + bjv;
            E[((size_t)(t*BN + b0+3))*VN + v] = a3 + bjv;
        }
    }
}

// K2: P[j][g] = b_ih[g]+b_hh[g] + emb[j] . W_ih[g]  (j==28 -> bias only / SOS)
__global__ __launch_bounds__(256) void k_pred(const float* __restrict__ emb,
        const float* __restrict__ Wih, const float* __restrict__ bih,
        const float* __restrict__ bhh, float* __restrict__ P)
{
    __shared__ float el[HID];
    const int tid = threadIdx.x, j = blockIdx.x;
    if (tid < 80) {
        float4 v4 = make_float4(0.f, 0.f, 0.f, 0.f);
        if (j < 28) v4 = ((const float4*)(emb + (size_t)j*HID))[tid];
        ((float4*)el)[tid] = v4;
    }
    __syncthreads();
    #pragma unroll
    for (int q = 0; q < 5; ++q) {
        const int r = q*256 + tid;
        float acc = bih[r] + bhh[r];
        const float4* wrow = (const float4*)(Wih + (size_t)r*HID);
        #pragma unroll 8
        for (int k4 = 0; k4 < 80; ++k4)
            acc += dot4(wrow[k4], ((const float4*)el)[k4]);
        P[(size_t)j*NG + r] = acc;
    }
}

// K3: greedy decode. 8 WGs per batch element (cluster), 256 threads each.
__global__ __launch_bounds__(256) void k_dec(const int* __restrict__ lengths,
        const float* __restrict__ Whh, const float* __restrict__ Wj,
        const float* __restrict__ E, const float* __restrict__ P,
        float* __restrict__ h2buf, float* __restrict__ plog,
        int* __restrict__ tags, float* __restrict__ out)
{
    __shared__ float P_lds[VN*ROWS];    // 18560 B
    __shared__ float Wjh[VN*UPS];       //  4640 B
    __shared__ float h_com[HID];
    __shared__ float h2st[HID];
    __shared__ float c_com[UPS];
    __shared__ float c2st[UPS];
    __shared__ float gates[ROWS];
    __shared__ float plog_l[SLICES*VN];
    __shared__ float lsum[VN];
    __shared__ float E_l[VN];
    __shared__ float pad_force[14000];  // pad LDS > 80KB -> exclusive CU residency

    const int tid = threadIdx.x;
    const int bid = blockIdx.x;
    const int b = bid & 31, slice = bid >> 5;
    const int rg = tid >> 3, kg = tid & 7;
    const int lane = tid & 63;

    int len = lengths[b];
    if (len > TN) len = TN;
    if (len < 0) {  // never true; keeps pad_force allocated
        pad_force[tid] = (float)tid;
        h_com[tid & 255] = pad_force[(tid*7) & 13999];
    }

    // --- load W_hh slice into registers: 5 rows x 40 cols per thread ---
    float4 wq[50];
    #pragma unroll
    for (int q = 0; q < 5; ++q) {
        const int r = rg*5 + q;
        const int gt = r / 40, u = r - gt*40;
        const float4* wrow = (const float4*)(Whh + ((size_t)(gt*HID + slice*UPS + u))*HID + kg*40);
        #pragma unroll
        for (int jb = 0; jb < 10; ++jb) wq[q*10 + jb] = wrow[jb];
    }
    // --- P slice to LDS ---
    for (int i = tid; i < VN*ROWS; i += 256) {
        const int jj = i / ROWS, r = i - jj*ROWS;
        const int gt = r / 40, u = r - gt*40;
        P_lds[i] = P[(size_t)jj*NG + gt*HID + slice*UPS + u];
    }
    // --- W_joint hidden-slice to LDS ---
    for (int i = tid; i < VN*UPS; i += 256) {
        const int v = i / UPS, k = i - v*UPS;
        Wjh[i] = Wj[(size_t)v*JW + ENCD + slice*UPS + k];
    }
    for (int i = tid; i < HID; i += 256) h_com[i] = 0.f;
    if (tid < UPS) c_com[tid] = 0.f;
    if (slice == 0) for (int i = tid; i < 512; i += 256) out[b*512 + i] = -1.0f;
    __syncthreads();

    float lps = 0.f;
    int pos = 0, jrow = 28, n = 0;
    bool dirty = true;

    for (int t = 0; t < len; ++t) {
        __syncthreads();
        if (tid < VN) E_l[tid] = E[((size_t)(t*BN + b))*VN + tid];
        __syncthreads();

        for (int s = 0; s < 4; ++s) {
            if (dirty) {
                // ================= FULL STEP =================
                __syncthreads();
                float acc[5] = {0.f, 0.f, 0.f, 0.f, 0.f};
                #pragma unroll
                for (int jb = 0; jb < 10; ++jb) {
                    float4 hv = *(const float4*)(h_com + kg*40 + jb*4);
                    #pragma unroll
                    for (int q = 0; q < 5; ++q) acc[q] += dot4(wq[q*10 + jb], hv);
                }
                #pragma unroll
                for (int q = 0; q < 5; ++q) {
                    acc[q] += __shfl_xor(acc[q], 1);
                    acc[q] += __shfl_xor(acc[q], 2);
                    acc[q] += __shfl_xor(acc[q], 4);
                }
                if (kg == 0) {
                    #pragma unroll
                    for (int q = 0; q < 5; ++q) {
                        const int r = rg*5 + q;
                        gates[r] = acc[q] + P_lds[jrow*ROWS + r];
                    }
                }
                __syncthreads();
                if (tid < UPS) {
                    const float gi = gates[tid],      gf = gates[40+tid];
                    const float gg = gates[80+tid],   go = gates[120+tid];
                    const float ii = 1.f/(1.f+expf(-gi));
                    const float ff = 1.f/(1.f+expf(-gf));
                    const float oo = 1.f/(1.f+expf(-go));
                    const float G  = tanhf(gg);
                    const float c2 = ff*c_com[tid] + ii*G;
                    c2st[tid] = c2;
                    const float h2 = oo * tanhf(c2);
                    h2st[slice*UPS + tid] = h2;
                    __hip_atomic_store(&h2buf[((size_t)((n&1)*BN + b))*HID + slice*UPS + tid],
                                       h2, __ATOMIC_RELAXED, __HIP_MEMORY_SCOPE_AGENT);
                }
                __syncthreads();
                if (tid < 232) {
                    const int v = tid >> 3, k8 = tid & 7;
                    float pp = 0.f;
                    #pragma unroll
                    for (int m2 = 0; m2 < 5; ++m2)
                        pp += Wjh[v*UPS + k8*5 + m2] * h2st[slice*UPS + k8*5 + m2];
                    pp += __shfl_xor(pp, 1);
                    pp += __shfl_xor(pp, 2);
                    pp += __shfl_xor(pp, 4);
                    if (k8 == 0)
                        __hip_atomic_store(&plog[(((size_t)((n&1)*BN + b))*SLICES + slice)*VN + v],
                                           pp, __ATOMIC_RELAXED, __HIP_MEMORY_SCOPE_AGENT);
                }
                __syncthreads();   // drains all agent stores (vmcnt) per wave
                if (tid == 0) {
                    __threadfence();
                    __hip_atomic_store(&tags[b*SLICES + slice], n + 1,
                                       __ATOMIC_RELEASE, __HIP_MEMORY_SCOPE_AGENT);
                    const int need = n + 1;
                    long cap = 0;
                    for (;;) {
                        int mn = 0x7fffffff;
                        #pragma unroll
                        for (int j2 = 0; j2 < 8; ++j2) {
                            int tg = __hip_atomic_load(&tags[b*SLICES + j2],
                                         __ATOMIC_RELAXED, __HIP_MEMORY_SCOPE_AGENT);
                            mn = tg < mn ? tg : mn;
                        }
                        if (mn >= need) break;
                        if (++cap > (1L << 28)) break;   // safety valve (never hit when correct)
                    }
                    __threadfence();
                }
                __syncthreads();
                {
                    const size_t hb = ((size_t)((n&1)*BN + b))*HID;
                    float r0 = __hip_atomic_load(&h2buf[hb + tid],
                                   __ATOMIC_RELAXED, __HIP_MEMORY_SCOPE_AGENT);
                    h2st[tid] = r0;
                    if (tid < 64) {
                        float r1 = __hip_atomic_load(&h2buf[hb + 256 + tid],
                                       __ATOMIC_RELAXED, __HIP_MEMORY_SCOPE_AGENT);
                        h2st[256 + tid] = r1;
                    }
                    if (tid < 232) {
                        const int j2 = tid / VN, v = tid - j2*VN;
                        plog_l[j2*VN + v] = __hip_atomic_load(
                            &plog[(((size_t)((n&1)*BN + b))*SLICES + j2)*VN + v],
                            __ATOMIC_RELAXED, __HIP_MEMORY_SCOPE_AGENT);
                    }
                }
                __syncthreads();
                if (tid < VN) {
                    float sA = 0.f;
                    #pragma unroll
                    for (int j2 = 0; j2 < 8; ++j2) sA += plog_l[j2*VN + tid];
                    lsum[tid] = sA;
                }
                __syncthreads();
                n++;
            }
            // ============ COMMON: logits -> argmax -> update ============
            const float Lv = (lane < VN) ? (E_l[lane] + lsum[lane]) : -INFINITY;
            float m = Lv; int ai = lane;
            #pragma unroll
            for (int d = 1; d < 64; d <<= 1) {
                const float om = __shfl_xor(m, d);
                const int   oi = __shfl_xor(ai, d);
                if (om > m || (om == m && oi < ai)) { m = om; ai = oi; }
            }
            float e = (lane < VN) ? expf(Lv - m) : 0.f;
            #pragma unroll
            for (int d = 1; d < 64; d <<= 1) e += __shfl_xor(e, d);
            lps += -logf(e);                 // v = logits[argmax] - lse = -log(sum exp(L-m))

            if (ai == BLANKI) { dirty = false; break; }
            // emit
            if (slice == 0 && tid == 0) out[b*512 + pos] = (float)ai;
            pos++;
            h_com[tid] = h2st[tid];
            if (tid < 64) h_com[256 + tid] = h2st[256 + tid];
            if (tid < UPS) c_com[tid] = c2st[tid];
            jrow = ai;
            dirty = true;
        }
    }

    if (slice == 0 && tid == 0) {
        out[16384 + b] = (float)pos;   // n_symbols
        out[16416 + b] = lps;          // logp_sum
    }
}

extern "C" void kernel_launch(void* const* d_in, const int* in_sizes, int n_in,
                              void* d_out, int out_size, void* d_ws, size_t ws_size,
                              hipStream_t stream) {
    const float* x    = (const float*)d_in[0];
    const int* lens   = (const int*)  d_in[1];
    const float* emb  = (const float*)d_in[2];
    const float* Wih  = (const float*)d_in[3];
    const float* Whh  = (const float*)d_in[4];
    const float* bih  = (const float*)d_in[5];
    const float* bhh  = (const float*)d_in[6];
    const float* Wj   = (const float*)d_in[7];
    const float* bj   = (const float*)d_in[8];
    float* out = (float*)d_out;
    float* ws  = (float*)d_ws;

    float* E     = ws + E_OFF;
    float* P     = ws + P_OFF;
    float* h2buf = ws + H2_OFF;
    float* plogb = ws + PL_OFF;
    int*   tags  = (int*)(ws + TAG_OFF);

    hipLaunchKernelGGL(k_enc,  dim3(1024), dim3(256), 0, stream, x, Wj, bj, E, tags);
    hipLaunchKernelGGL(k_pred, dim3(29),   dim3(256), 0, stream, emb, Wih, bih, bhh, P);
    hipLaunchKernelGGL(k_dec,  dim3(256),  dim3(256), 0, stream,
                       lens, Whh, Wj, E, P, h2buf, plogb, tags, out);
}

// Round 2
// 2010.366 us; speedup vs baseline: 2.5520x; 2.5520x over previous
//
#include <hip/hip_runtime.h>
#include <math.h>

typedef unsigned long long u64;
typedef unsigned int u32;

#define BN 32
#define TN 128
#define ENCD 1024
#define HID 320
#define NG 1280       // 4*HID
#define VN 29
#define BLANKI 28
#define SLICES 8
#define UPS 40        // hidden units per slice
#define ROWS 160      // gate rows per slice (4*UPS)
#define JW 1344       // ENC+HID
#define XSTRIDE 70    // u64 words per (parity,b,slice) region; 69 used
#define NPOLL (SLICES*69)   // 552 words each WG polls per step

// workspace layout (floats)
#define E_OFF   0
#define E_SZ    (TN*BN*VN)          // 118784
#define P_OFF   (E_OFF + E_SZ)
#define P_SZ    (VN*NG)             // 37120
#define X_OFF   (P_OFF + P_SZ)      // 155904 floats -> byte 623616, 8B aligned
#define X_U64S  (2*BN*SLICES*XSTRIDE)   // 35840 u64 = 286720 B

__device__ __forceinline__ float dot4(float4 a, float4 b) {
    return a.x*b.x + a.y*b.y + a.z*b.z + a.w*b.w;
}

// K1: E[t][b][v] = b_joint[v] + x[t][b][:1024] . W_joint[v][:1024]; zeroes XCHG.
__global__ __launch_bounds__(256) void k_enc(const float* __restrict__ x,
        const float* __restrict__ Wj, const float* __restrict__ bj,
        float* __restrict__ E, u64* __restrict__ xchg)
{
    __shared__ float xl[4][1056];   // 4 batch rows, padded every 128 floats by 4
    const int tid = threadIdx.x;
    const int blk = blockIdx.x;
    const int t = blk >> 3, b0 = (blk & 7) * 4;

    if (tid < 35) xchg[(size_t)blk*35 + tid] = 0ull;   // 1024*35 == X_U64S

    #pragma unroll
    for (int bb = 0; bb < 4; ++bb) {
        const float4* src = (const float4*)(x + ((size_t)(t*BN + b0 + bb))*ENCD);
        float4 v4 = src[tid];
        ((float4*)&xl[bb][0])[tid + (tid >> 5)] = v4;   // padded store
    }
    __syncthreads();
    if (tid < 232) {
        const int v = tid >> 3, k8 = tid & 7;
        float a0=0.f, a1=0.f, a2=0.f, a3=0.f;
        const float4* wrow = (const float4*)(Wj + (size_t)v*JW) + k8*32;
        const float4* x0 = ((const float4*)&xl[0][0]) + k8*33;
        const float4* x1 = ((const float4*)&xl[1][0]) + k8*33;
        const float4* x2 = ((const float4*)&xl[2][0]) + k8*33;
        const float4* x3 = ((const float4*)&xl[3][0]) + k8*33;
        #pragma unroll 4
        for (int m = 0; m < 32; ++m) {
            float4 w4 = wrow[m];
            a0 += dot4(w4, x0[m]);
            a1 += dot4(w4, x1[m]);
            a2 += dot4(w4, x2[m]);
            a3 += dot4(w4, x3[m]);
        }
        #pragma unroll
        for (int d = 1; d < 8; d <<= 1) {
            a0 += __shfl_xor(a0, d); a1 += __shfl_xor(a1, d);
            a2 += __shfl_xor(a2, d); a3 += __shfl_xor(a3, d);
        }
        if (k8 == 0) {
            float bjv = bj[v];
            E[((size_t)(t*BN + b0+0))*VN + v] = a0 + bjv;
            E[((size_t)(t*BN + b0+1))*VN + v] = a1 + bjv;
            E[((size_t)(t*BN + b0+2))*VN + v] = a2 + bjv;
            E[((size_t)(t*BN + b0+3))*VN + v] = a3 + bjv;
        }
    }
}

// K2: P[j][g] = b_ih[g]+b_hh[g] + emb[j] . W_ih[g]  (j==28 -> bias only / SOS)
__global__ __launch_bounds__(256) void k_pred(const float* __restrict__ emb,
        const float* __restrict__ Wih, const float* __restrict__ bih,
        const float* __restrict__ bhh, float* __restrict__ P)
{
    __shared__ float el[HID];
    const int tid = threadIdx.x, j = blockIdx.x;
    if (tid < 80) {
        float4 v4 = make_float4(0.f, 0.f, 0.f, 0.f);
        if (j < 28) v4 = ((const float4*)(emb + (size_t)j*HID))[tid];
        ((float4*)el)[tid] = v4;
    }
    __syncthreads();
    #pragma unroll
    for (int q = 0; q < 5; ++q) {
        const int r = q*256 + tid;
        float acc = bih[r] + bhh[r];
        const float4* wrow = (const float4*)(Wih + (size_t)r*HID);
        #pragma unroll 8
        for (int k4 = 0; k4 < 80; ++k4)
            acc += dot4(wrow[k4], ((const float4*)el)[k4]);
        P[(size_t)j*NG + r] = acc;
    }
}

// K3: greedy decode. 8 WGs per batch element; self-validating 64-bit exchange.
__global__ __launch_bounds__(256, 1) void k_dec(const int* __restrict__ lengths,
        const float* __restrict__ Whh, const float* __restrict__ Wj,
        const float* __restrict__ E, const float* __restrict__ P,
        u64* __restrict__ xchg, float* __restrict__ out)
{
    __shared__ float P_lds[VN*ROWS];    // 18560 B
    __shared__ float Wjh[VN*UPS];       //  4640 B
    __shared__ float h_com[HID];
    __shared__ float h2st[HID];
    __shared__ float c_com[UPS];
    __shared__ float c2st[UPS];
    __shared__ float gates[ROWS];
    __shared__ float plog_l[SLICES*VN];
    __shared__ float lsum[VN];
    __shared__ float E_l[VN];
    __shared__ float pad_force[14000];  // pad LDS > 80KB -> exclusive CU residency

    const int tid = threadIdx.x;
    const int bid = blockIdx.x;
    const int b = bid & 31, slice = bid >> 5;
    const int rg = tid >> 3, kg = tid & 7;
    const int lane = tid & 63;

    int len = lengths[b];
    if (len > TN) len = TN;
    if (len < 0) {  // never true; keeps pad_force allocated
        pad_force[tid] = (float)tid;
        h_com[tid & 255] = pad_force[(tid*7) & 13999];
    }

    // --- load W_hh slice into registers: 5 rows x 40 cols per thread ---
    float4 wq[50];
    #pragma unroll
    for (int q = 0; q < 5; ++q) {
        const int r = rg*5 + q;
        const int gt = r / 40, u = r - gt*40;
        const float4* wrow = (const float4*)(Whh + ((size_t)(gt*HID + slice*UPS + u))*HID + kg*40);
        #pragma unroll
        for (int jb = 0; jb < 10; ++jb) wq[q*10 + jb] = wrow[jb];
    }
    // --- P slice to LDS ---
    for (int i = tid; i < VN*ROWS; i += 256) {
        const int jj = i / ROWS, r = i - jj*ROWS;
        const int gt = r / 40, u = r - gt*40;
        P_lds[i] = P[(size_t)jj*NG + gt*HID + slice*UPS + u];
    }
    // --- W_joint hidden-slice to LDS ---
    for (int i = tid; i < VN*UPS; i += 256) {
        const int v = i / UPS, k = i - v*UPS;
        Wjh[i] = Wj[(size_t)v*JW + ENCD + slice*UPS + k];
    }
    for (int i = tid; i < HID; i += 256) h_com[i] = 0.f;
    if (tid < UPS) c_com[tid] = 0.f;
    if (slice == 0) for (int i = tid; i < 512; i += 256) out[b*512 + i] = -1.0f;
    __syncthreads();

    float lps = 0.f;
    int pos = 0, jrow = 28, n = 1;    // n = full-step sequence number (seq 0 = invalid)
    bool dirty = true;

    for (int t = 0; t < len; ++t) {
        __syncthreads();
        if (tid < VN) E_l[tid] = E[((size_t)(t*BN + b))*VN + tid];
        __syncthreads();

        for (int s = 0; s < 4; ++s) {
            if (dirty) {
                // ================= FULL STEP =================
                __syncthreads();
                const int par = n & 1;
                const size_t mybase = ((size_t)(par*BN + b)*SLICES + slice)*XSTRIDE;
                float acc[5] = {0.f, 0.f, 0.f, 0.f, 0.f};
                #pragma unroll
                for (int jb = 0; jb < 10; ++jb) {
                    float4 hv = *(const float4*)(h_com + kg*40 + jb*4);
                    #pragma unroll
                    for (int q = 0; q < 5; ++q) acc[q] += dot4(wq[q*10 + jb], hv);
                }
                #pragma unroll
                for (int q = 0; q < 5; ++q) {
                    acc[q] += __shfl_xor(acc[q], 1);
                    acc[q] += __shfl_xor(acc[q], 2);
                    acc[q] += __shfl_xor(acc[q], 4);
                }
                if (kg == 0) {
                    #pragma unroll
                    for (int q = 0; q < 5; ++q) {
                        const int r = rg*5 + q;
                        gates[r] = acc[q] + P_lds[jrow*ROWS + r];
                    }
                }
                __syncthreads();
                if (tid < UPS) {
                    const float gi = gates[tid],      gf = gates[40+tid];
                    const float gg = gates[80+tid],   go = gates[120+tid];
                    const float ii = 1.f/(1.f+expf(-gi));
                    const float ff = 1.f/(1.f+expf(-gf));
                    const float oo = 1.f/(1.f+expf(-go));
                    const float G  = tanhf(gg);
                    const float c2 = ff*c_com[tid] + ii*G;
                    c2st[tid] = c2;
                    const float h2 = oo * tanhf(c2);
                    h2st[slice*UPS + tid] = h2;
                    const u64 pk = ((u64)(u32)n << 32) | (u64)__float_as_uint(h2);
                    __hip_atomic_store(&xchg[mybase + tid], pk,
                                       __ATOMIC_RELAXED, __HIP_MEMORY_SCOPE_AGENT);
                }
                __syncthreads();
                if (tid < 232) {
                    const int v = tid >> 3, k8 = tid & 7;
                    float pp = 0.f;
                    #pragma unroll
                    for (int m2 = 0; m2 < 5; ++m2)
                        pp += Wjh[v*UPS + k8*5 + m2] * h2st[slice*UPS + k8*5 + m2];
                    pp += __shfl_xor(pp, 1);
                    pp += __shfl_xor(pp, 2);
                    pp += __shfl_xor(pp, 4);
                    if (k8 == 0) {
                        const u64 pk = ((u64)(u32)n << 32) | (u64)__float_as_uint(pp);
                        __hip_atomic_store(&xchg[mybase + UPS + v], pk,
                                           __ATOMIC_RELAXED, __HIP_MEMORY_SCOPE_AGENT);
                    }
                }
                // ---- parallel poll: 552 self-validating words across 256 threads ----
                {
                    const size_t pbase = ((size_t)(par*BN + b)*SLICES)*XSTRIDE;
                    for (int i = tid; i < NPOLL; i += 256) {
                        const int j2 = i / 69, w = i - j2*69;
                        const u64* ap = &xchg[pbase + (size_t)j2*XSTRIDE + w];
                        u64 v; int cap = 0;
                        do {
                            v = __hip_atomic_load(ap, __ATOMIC_RELAXED,
                                                  __HIP_MEMORY_SCOPE_AGENT);
                        } while ((u32)(v >> 32) != (u32)n && ++cap < (1 << 22));
                        const float f = __uint_as_float((u32)v);
                        if (w < UPS) h2st[j2*UPS + w] = f;
                        else         plog_l[j2*VN + (w - UPS)] = f;
                    }
                }
                __syncthreads();
                if (tid < VN) {
                    float sA = 0.f;
                    #pragma unroll
                    for (int j2 = 0; j2 < 8; ++j2) sA += plog_l[j2*VN + tid];
                    lsum[tid] = sA;
                }
                __syncthreads();
                n++;
            }
            // ============ COMMON: logits -> argmax -> update ============
            const float Lv = (lane < VN) ? (E_l[lane] + lsum[lane]) : -INFINITY;
            float m = Lv; int ai = lane;
            #pragma unroll
            for (int d = 1; d < 64; d <<= 1) {
                const float om = __shfl_xor(m, d);
                const int   oi = __shfl_xor(ai, d);
                if (om > m || (om == m && oi < ai)) { m = om; ai = oi; }
            }
            float e = (lane < VN) ? expf(Lv - m) : 0.f;
            #pragma unroll
            for (int d = 1; d < 64; d <<= 1) e += __shfl_xor(e, d);
            lps += -logf(e);                 // v = logits[argmax] - lse

            if (ai == BLANKI) { dirty = false; break; }
            // emit
            if (slice == 0 && tid == 0) out[b*512 + pos] = (float)ai;
            pos++;
            h_com[tid] = h2st[tid];
            if (tid < 64) h_com[256 + tid] = h2st[256 + tid];
            if (tid < UPS) c_com[tid] = c2st[tid];
            jrow = ai;
            dirty = true;
        }
    }

    if (slice == 0 && tid == 0) {
        out[16384 + b] = (float)pos;   // n_symbols
        out[16416 + b] = lps;          // logp_sum
    }
}

extern "C" void kernel_launch(void* const* d_in, const int* in_sizes, int n_in,
                              void* d_out, int out_size, void* d_ws, size_t ws_size,
                              hipStream_t stream) {
    const float* x    = (const float*)d_in[0];
    const int* lens   = (const int*)  d_in[1];
    const float* emb  = (const float*)d_in[2];
    const float* Wih  = (const float*)d_in[3];
    const float* Whh  = (const float*)d_in[4];
    const float* bih  = (const float*)d_in[5];
    const float* bhh  = (const float*)d_in[6];
    const float* Wj   = (const float*)d_in[7];
    const float* bj   = (const float*)d_in[8];
    float* out = (float*)d_out;
    float* ws  = (float*)d_ws;

    float* E    = ws + E_OFF;
    float* P    = ws + P_OFF;
    u64*   xchg = (u64*)(ws + X_OFF);

    hipLaunchKernelGGL(k_enc,  dim3(1024), dim3(256), 0, stream, x, Wj, bj, E, xchg);
    hipLaunchKernelGGL(k_pred, dim3(29),   dim3(256), 0, stream, emb, Wih, bih, bhh, P);
    hipLaunchKernelGGL(k_dec,  dim3(256),  dim3(256), 0, stream,
                       lens, Whh, Wj, E, P, xchg, out);
}